// Round 15
// baseline (338.274 us; speedup 1.0000x reference)
//
#include <hip/hip_runtime.h>
#include <cstdint>

typedef unsigned short u16;
typedef __bf16 bf16x8 __attribute__((ext_vector_type(8)));
typedef float f32x4 __attribute__((ext_vector_type(4)));

#define M_DIM 8192
#define N_DIM 1024
#define I_DIM 1024
#define NDEG 8                    /* stored degrees d=1..8 */
#define K_DIM (I_DIM * NDEG)      /* 8192 */
#define BM 256
#define BN 128
#define BK 64
#define NT (K_DIM / BK)           /* 128 K-tiles */
#define B_TILE (BN * BK)          /* 8192 u16 = 16 KB */

__device__ __forceinline__ u16 f2bf(float f) {
    union { float f; uint32_t u; } v; v.f = f;
    return (u16)((v.u + 0x7FFFu + ((v.u >> 16) & 1u)) >> 16);
}

__device__ __forceinline__ void gload_lds16(const u16* g, u16* l) {
    auto lp = reinterpret_cast<__attribute__((address_space(3))) uint32_t*>(
        reinterpret_cast<uintptr_t>(l));
    __builtin_amdgcn_global_load_lds(reinterpret_cast<const uint32_t*>(g), lp, 16, 0, 0);
}

// ---------------------------------------------------------------------------
// fused prep helpers (r11-verified, unchanged)
// ---------------------------------------------------------------------------
__device__ __forceinline__ void do_transform_block(
    int blk, int t, const float* __restrict__ coeffs,
    u16* __restrict__ Bt, float* __restrict__ bias, float (*lds)[292])
{
    int bi = blk >> 5, bo = blk & 31;
    int i0 = bi * 32, o0 = bo * 32;

    {
        int r = t >> 3, s = t & 7;
        const float4* src = (const float4*)(coeffs + ((size_t)(i0 + r) * N_DIM + o0) * 9);
#pragma unroll
        for (int j = 0; j < 9; ++j) {
            float4 v = src[s * 9 + j];
            *(float4*)&lds[r][(s * 9 + j) * 4] = v;
        }
    }
    __syncthreads();

    {
        int c = t >> 3, s2 = t & 7;
        u16 ob[32];
#pragma unroll
        for (int rr = 0; rr < 4; ++rr)
#pragma unroll
            for (int dd = 0; dd < 8; ++dd)
                ob[rr * 8 + dd] = f2bf(lds[s2 * 4 + rr][c * 9 + 1 + dd]);
        uint4* dst = (uint4*)(Bt + (size_t)(o0 + c) * K_DIM + (size_t)i0 * 8 + s2 * 32);
        const uint4* sp = (const uint4*)ob;
#pragma unroll
        for (int u = 0; u < 4; ++u) dst[u] = sp[u];
    }

    if (t < 32) {
        float sum = 0.f;
#pragma unroll
        for (int rr = 0; rr < 32; ++rr) sum += lds[rr][t * 9];
        atomicAdd(&bias[o0 + t], sum);
    }
}

__device__ __forceinline__ void do_basis_thread(
    int gt, const float* __restrict__ x,
    const float* __restrict__ pa, const float* __restrict__ pb,
    const float* __restrict__ pc, const float* __restrict__ pd,
    const float* __restrict__ pq, u16* __restrict__ A, int row0)
{
    int rb = gt >> 7;
    int g  = gt & 127;
    int i0 = g << 3;
    int b  = row0 + rb;

    float a = *pa, bb = *pb, c = *pc, d = *pd, q = *pq;
    float ab = a * bb, cd = c * d, abcd = ab * cd;

    float qp[17];
    qp[0] = 1.f;
#pragma unroll
    for (int k = 1; k <= 16; ++k) qp[k] = qp[k - 1] * q;

    float den1 = 1.f + abcd * q * q;
    float c1x = 2.f * (1.f + ab * q) / den1;
    float c1c = -(a + bb) * (1.f + cd * q) / den1;

    float An[9], Cn[9], Sn[9];
#pragma unroll
    for (int n = 2; n <= 8; ++n) {
        float t1 = 1.f - ab * qp[n - 1];
        float t2 = 1.f - cd * qp[n - 1];
        float t3 = 1.f - abcd * qp[2 * n - 2];
        float t4 = 1.f - abcd * qp[2 * n - 1];
        float t5 = 1.f - abcd * qp[2 * n];
        An[n] = (t1 * t2 * t3) / (t4 * t5);
        Cn[n] = ((1.f - qp[n]) * t1 * t2 * t3) / (t3 * t4);
        Sn[n] = 1.f / (1.f - qp[n]);
    }

    const float4* x4 = (const float4*)(x + (size_t)b * I_DIM + i0);
    float4 v0 = x4[0], v1 = x4[1];
    float xv[8] = {v0.x, v0.y, v0.z, v0.w, v1.x, v1.y, v1.z, v1.w};

    u16 ob[64];
#pragma unroll
    for (int j = 0; j < 8; ++j) {
        float xj = xv[j];
        float p1 = c1x * xj + c1c;
        ob[j * 8 + 0] = f2bf(p1);
        float pm2 = 1.f, pm1 = p1;
#pragma unroll
        for (int n = 2; n <= 8; ++n) {
            float pn = ((2.f * xj - An[n]) * pm1 - Cn[n] * pm2) * Sn[n];
            ob[j * 8 + n - 1] = f2bf(pn);
            pm2 = pm1; pm1 = pn;
        }
    }

    uint4* dst = (uint4*)(A + (size_t)rb * K_DIM + (size_t)i0 * 8);
    const uint4* s = (const uint4*)ob;
#pragma unroll
    for (int u = 0; u < 8; ++u) dst[u] = s[u];
}

__global__ __launch_bounds__(256) void aw_prep(
    const float* __restrict__ coeffs, const float* __restrict__ x,
    const float* __restrict__ pa, const float* __restrict__ pb,
    const float* __restrict__ pc, const float* __restrict__ pd,
    const float* __restrict__ pq,
    u16* __restrict__ Bt, float* __restrict__ bias, u16* __restrict__ A)
{
    __shared__ float lds[32][292];
    int blk = blockIdx.x;
    int t = threadIdx.x;
    if (blk < 1024) {
        do_transform_block(blk, t, coeffs, Bt, bias, lds);
    } else {
        int gt = (blk - 1024) * 256 + t;
        do_basis_thread(gt, x, pa, pb, pc, pd, pq, A, 0);
    }
}

__global__ __launch_bounds__(256) void aw_transform(
    const float* __restrict__ coeffs, u16* __restrict__ Bt, float* __restrict__ bias)
{
    __shared__ float lds[32][292];
    do_transform_block(blockIdx.x, threadIdx.x, coeffs, Bt, bias, lds);
}

__global__ void aw_basis(const float* __restrict__ x,
                         const float* __restrict__ pa, const float* __restrict__ pb,
                         const float* __restrict__ pc, const float* __restrict__ pd,
                         const float* __restrict__ pq,
                         u16* __restrict__ A, int row0)
{
    do_basis_thread(blockIdx.x * 256 + threadIdx.x, x, pa, pb, pc, pd, pq, A, row0);
}

// ---------------------------------------------------------------------------
// Kernel 2: A-DIRECT-TO-REG GEMM (A bypasses LDS; B via verified LDS path).
// BM=256 x BN=128, BK=64, 512 thr = 8 waves: 4 quadrant-owners (2M x 2N,
// 128x64/wave = 8x4 frags) x 2 K-halves (r8 geometry). Each lane's A-frag is
// a contiguous 16B chunk A[row][slot*8..+8] -> loaded DIRECTLY global->reg
// (L2 absorbs the x2 wc-duplication). LDS/tile drops 144->48 KB (B stage 16
// + B reads 32), far under the 1242-cyc MFMA floor -> MFMA-bound.
// A-regs double-buffered in named sets pa/qa (rule #20). Per tile t:
//   stageB(t+2)->buf(t+2)%3 ; loadA(t+1)->next set ; 4 ds_read B(t) ;
//   32 MFMA (setprio) [compiler auto-vmcnt covers A(t), issued 1 tile ago] ;
//   vmcnt(8) [>=8 newer issues exist => B(t+1) retired under ANY issue
//   order -- audited incl. tails] ; s_barrier.
// Explicit __syncthreads() before merge epilogue (fixes r8's latent skew
// race). Merge region = 128 KB LDS (B bufs alias its first 48 KB).
// ---------------------------------------------------------------------------
__global__ __launch_bounds__(512, 1) void aw_gemm(
    const u16* __restrict__ A,
    const u16* __restrict__ B,
    const float* __restrict__ bias,
    float* __restrict__ C,
    int row0, int rowBlocks)
{
    __shared__ alignas(16) unsigned char smemraw[131072];   // 128 KB
    u16* Bs = (u16*)smemraw;                                // 3 x 16 KB bufs

    int nwg = rowBlocks * 8;
    int bid = blockIdx.x;
    int per = nwg >> 3;
    int logical = (bid & 7) * per + (bid >> 3);
    int rowBlk = logical >> 3;       // 8 col-blocks
    int colBlk = logical & 7;

    const int tid  = threadIdx.x;
    const int lane = tid & 63;
    const int wid  = tid >> 6;
    const int quad = wid & 3;        // C-quadrant (2M x 2N)
    const int wr   = quad >> 1;      // 0..1 (128-row half)
    const int wc   = quad & 1;       // 0..1 (64-col half)
    const int myKs = wid >> 2;       // 0..1 (32-wide K half of each tile)

    // --- A: per-lane direct global base (row + k-slot), frags at imm offs ---
    const int aRow  = rowBlk * BM + wr * 128 + (lane & 15);
    const int aSlot = myKs * 4 + (lane >> 4);               // 0..7
    const u16* aF0 = A + (size_t)aRow * K_DIM + aSlot * 8;

    // --- B staging (2 gload_lds per thread; source slot pre-swizzled) ---
    const u16* gB[2];
    int ldsB[2];
#pragma unroll
    for (int j = 0; j < 2; ++j) {
        int idx = j * 512 + tid;
        int r = idx >> 3, sl = idx & 7;
        gB[j] = B + (size_t)colBlk * BN * K_DIM + (size_t)r * K_DIM + ((sl ^ (r & 7)) << 3);
        ldsB[j] = idx << 3;
    }

    // --- B fragment byte-offsets for this wave's ks-half (swizzled reads) ---
    int offB[4];
#pragma unroll
    for (int ni = 0; ni < 4; ++ni) {
        int r = wc * 64 + ni * 16 + (lane & 15);
        int s = myKs * 4 + (lane >> 4);
        offB[ni] = r * 128 + ((s ^ (r & 7)) << 4);
    }

    f32x4 acc[8][4];
#pragma unroll
    for (int mi = 0; mi < 8; ++mi)
#pragma unroll
        for (int ni = 0; ni < 4; ++ni)
            acc[mi][ni] = (f32x4){0.f, 0.f, 0.f, 0.f};

    auto stageB = [&](int kt, int buf) {
        const int k0 = kt * BK;
        u16* dB = Bs + buf * B_TILE;
        gload_lds16(gB[0] + k0, dB + ldsB[0]);
        gload_lds16(gB[1] + k0, dB + ldsB[1]);
    };
    auto loadA = [&](bf16x8 (&fa)[8], int kt) {
        const u16* p = aF0 + (size_t)kt * BK;
#pragma unroll
        for (int mi = 0; mi < 8; ++mi)
            fa[mi] = *(const bf16x8*)(p + (size_t)mi * (16 * K_DIM));
    };
    auto domfma = [&](bf16x8 (&fa)[8], int buf) {
        const char* bB = (const char*)(Bs + buf * B_TILE);
        bf16x8 fb[4];
#pragma unroll
        for (int ni = 0; ni < 4; ++ni) fb[ni] = *(const bf16x8*)(bB + offB[ni]);
        __builtin_amdgcn_s_setprio(1);
#pragma unroll
        for (int mi = 0; mi < 8; ++mi)
#pragma unroll
            for (int ni = 0; ni < 4; ++ni)
                acc[mi][ni] = __builtin_amdgcn_mfma_f32_16x16x32_bf16(
                    fa[mi], fb[ni], acc[mi][ni], 0, 0, 0);
        __builtin_amdgcn_s_setprio(0);
    };

#define TILE_IT(T, CUR, NXT)                                                  \
    do {                                                                      \
        int b2 = buf + 2; if (b2 >= 3) b2 -= 3;                               \
        if ((T) + 2 < NT) stageB((T) + 2, b2);                                \
        if ((T) + 1 < NT) loadA(NXT, (T) + 1);                                \
        domfma(CUR, buf);                                                     \
        if ((T) + 1 < NT) {                                                   \
            asm volatile("s_waitcnt vmcnt(8)" ::: "memory");                  \
            __builtin_amdgcn_s_barrier();                                     \
        }                                                                     \
        buf += 1; if (buf >= 3) buf -= 3;                                     \
    } while (0)

    // prologue: stage B(0),B(1); load A(0); drain B0 (vmcnt(8): 12 -> 8)
    stageB(0, 0);
    stageB(1, 1);
    bf16x8 pa[8], qa[8];
    loadA(pa, 0);
    asm volatile("s_waitcnt vmcnt(8)" ::: "memory");
    __builtin_amdgcn_s_barrier();

    int buf = 0;
    for (int t = 0; t < NT; t += 2) {
        TILE_IT(t,     pa, qa);
        TILE_IT(t + 1, qa, pa);
    }
#undef TILE_IT

    // ---- epilogue: merge K-half partials via 128 KB LDS ----
    __syncthreads();                    // all waves done with Bs before reuse
    float* red = (float*)smemraw;
    if (myKs == 1) {
        f32x4* dst = (f32x4*)red + quad * 2048;   // 32 KB per quadrant
#pragma unroll
        for (int mi = 0; mi < 8; ++mi)
#pragma unroll
            for (int ni = 0; ni < 4; ++ni)
                dst[(mi * 4 + ni) * 64 + lane] = acc[mi][ni];
    }
    __syncthreads();
    if (myKs == 0) {
        const f32x4* src = (const f32x4*)red + quad * 2048;
#pragma unroll
        for (int mi = 0; mi < 8; ++mi)
#pragma unroll
            for (int ni = 0; ni < 4; ++ni) {
                f32x4 p = src[(mi * 4 + ni) * 64 + lane];
                acc[mi][ni] += p;
            }

        // D layout col=lane&15, row=(lane>>4)*4+j  [m89]
        int gRow = row0 + rowBlk * BM + wr * 128;
        int gCol = colBlk * BN + wc * 64;
#pragma unroll
        for (int mi = 0; mi < 8; ++mi) {
#pragma unroll
            for (int ni = 0; ni < 4; ++ni) {
                int rr = gRow + mi * 16 + ((lane >> 4) << 2);
                int cc = gCol + ni * 16 + (lane & 15);
                float bv = bias[cc];
                float* dst = C + (size_t)rr * N_DIM + cc;
#pragma unroll
                for (int j = 0; j < 4; ++j) dst[(size_t)j * N_DIM] = acc[mi][ni][j] + bv;
            }
        }
    }
}

// ---------------------------------------------------------------------------
extern "C" void kernel_launch(void* const* d_in, const int* in_sizes, int n_in,
                              void* d_out, int out_size, void* d_ws, size_t ws_size,
                              hipStream_t stream)
{
    const float* x      = (const float*)d_in[0];
    const float* pa     = (const float*)d_in[1];
    const float* pb     = (const float*)d_in[2];
    const float* pc     = (const float*)d_in[3];
    const float* pd     = (const float*)d_in[4];
    const float* pq     = (const float*)d_in[5];
    const float* coeffs = (const float*)d_in[6];
    float* out = (float*)d_out;

    float* bias = (float*)d_ws;
    const size_t biasBytes = 4096;
    u16* Bt = (u16*)((char*)d_ws + biasBytes);
    const size_t btBytes = (size_t)N_DIM * K_DIM * sizeof(u16);   // 16.8 MB
    u16* Abuf = (u16*)((char*)d_ws + biasBytes + btBytes);
    size_t used = biasBytes + btBytes;
    size_t avail = ws_size > used ? ws_size - used : 0;
    const size_t aFullBytes = (size_t)M_DIM * K_DIM * sizeof(u16);  // 134 MB

    hipMemsetAsync(bias, 0, N_DIM * sizeof(float), stream);

    if (avail >= aFullBytes) {
        aw_prep<<<1024 + (M_DIM * 128) / 256, 256, 0, stream>>>(
            coeffs, x, pa, pb, pc, pd, pq, Bt, bias, Abuf);
        aw_gemm<<<(M_DIM / BM) * 8, 512, 0, stream>>>(Abuf, Bt, bias, out, 0, M_DIM / BM);
    } else {
        int chunk = M_DIM;
        while (chunk > 256 && (size_t)chunk * K_DIM * sizeof(u16) > avail) chunk >>= 1;
        aw_transform<<<1024, 256, 0, stream>>>(coeffs, Bt, bias);
        for (int row0 = 0; row0 < M_DIM; row0 += chunk) {
            aw_basis<<<(chunk * 128) / 256, 256, 0, stream>>>(x, pa, pb, pc, pd, pq, Abuf, row0);
            aw_gemm<<<(chunk / BM) * 8, 512, 0, stream>>>(Abuf, Bt, bias, out, row0, chunk / BM);
        }
    }
}

// Round 16
// 202.300 us; speedup vs baseline: 1.6721x; 1.6721x over previous
//
#include <hip/hip_runtime.h>
#include <cstdint>

typedef unsigned short u16;
typedef __bf16 bf16x8 __attribute__((ext_vector_type(8)));
typedef float f32x4 __attribute__((ext_vector_type(4)));

#define M_DIM 8192
#define N_DIM 1024
#define I_DIM 1024
#define NDEG 8                    /* stored degrees d=1..8 */
#define K_DIM (I_DIM * NDEG)      /* 8192 */
#define BM 256
#define BN 256
#define BK 64
#define NT_FULL (K_DIM / BK)      /* 128 K-tiles */
#define A_TILE (BM * BK)          /* 16384 u16 = 32 KB */
#define B_TILE (BN * BK)          /* 16384 u16 = 32 KB */

__device__ __forceinline__ u16 f2bf(float f) {
    union { float f; uint32_t u; } v; v.f = f;
    return (u16)((v.u + 0x7FFFu + ((v.u >> 16) & 1u)) >> 16);
}

__device__ __forceinline__ void gload_lds16(const u16* g, u16* l) {
    auto lp = reinterpret_cast<__attribute__((address_space(3))) uint32_t*>(
        reinterpret_cast<uintptr_t>(l));
    __builtin_amdgcn_global_load_lds(reinterpret_cast<const uint32_t*>(g), lp, 16, 0, 0);
}

// ---------------------------------------------------------------------------
// fused prep helpers (r11-verified, unchanged)
// ---------------------------------------------------------------------------
__device__ __forceinline__ void do_transform_block(
    int blk, int t, const float* __restrict__ coeffs,
    u16* __restrict__ Bt, float* __restrict__ bias, float (*lds)[292])
{
    int bi = blk >> 5, bo = blk & 31;
    int i0 = bi * 32, o0 = bo * 32;

    {
        int r = t >> 3, s = t & 7;
        const float4* src = (const float4*)(coeffs + ((size_t)(i0 + r) * N_DIM + o0) * 9);
#pragma unroll
        for (int j = 0; j < 9; ++j) {
            float4 v = src[s * 9 + j];
            *(float4*)&lds[r][(s * 9 + j) * 4] = v;
        }
    }
    __syncthreads();

    {
        int c = t >> 3, s2 = t & 7;
        u16 ob[32];
#pragma unroll
        for (int rr = 0; rr < 4; ++rr)
#pragma unroll
            for (int dd = 0; dd < 8; ++dd)
                ob[rr * 8 + dd] = f2bf(lds[s2 * 4 + rr][c * 9 + 1 + dd]);
        uint4* dst = (uint4*)(Bt + (size_t)(o0 + c) * K_DIM + (size_t)i0 * 8 + s2 * 32);
        const uint4* sp = (const uint4*)ob;
#pragma unroll
        for (int u = 0; u < 4; ++u) dst[u] = sp[u];
    }

    if (t < 32) {
        float sum = 0.f;
#pragma unroll
        for (int rr = 0; rr < 32; ++rr) sum += lds[rr][t * 9];
        atomicAdd(&bias[o0 + t], sum);
    }
}

__device__ __forceinline__ void do_basis_thread(
    int gt, const float* __restrict__ x,
    const float* __restrict__ pa, const float* __restrict__ pb,
    const float* __restrict__ pc, const float* __restrict__ pd,
    const float* __restrict__ pq, u16* __restrict__ A, int row0)
{
    int rb = gt >> 7;
    int g  = gt & 127;
    int i0 = g << 3;
    int b  = row0 + rb;

    float a = *pa, bb = *pb, c = *pc, d = *pd, q = *pq;
    float ab = a * bb, cd = c * d, abcd = ab * cd;

    float qp[17];
    qp[0] = 1.f;
#pragma unroll
    for (int k = 1; k <= 16; ++k) qp[k] = qp[k - 1] * q;

    float den1 = 1.f + abcd * q * q;
    float c1x = 2.f * (1.f + ab * q) / den1;
    float c1c = -(a + bb) * (1.f + cd * q) / den1;

    float An[9], Cn[9], Sn[9];
#pragma unroll
    for (int n = 2; n <= 8; ++n) {
        float t1 = 1.f - ab * qp[n - 1];
        float t2 = 1.f - cd * qp[n - 1];
        float t3 = 1.f - abcd * qp[2 * n - 2];
        float t4 = 1.f - abcd * qp[2 * n - 1];
        float t5 = 1.f - abcd * qp[2 * n];
        An[n] = (t1 * t2 * t3) / (t4 * t5);
        Cn[n] = ((1.f - qp[n]) * t1 * t2 * t3) / (t3 * t4);
        Sn[n] = 1.f / (1.f - qp[n]);
    }

    const float4* x4 = (const float4*)(x + (size_t)b * I_DIM + i0);
    float4 v0 = x4[0], v1 = x4[1];
    float xv[8] = {v0.x, v0.y, v0.z, v0.w, v1.x, v1.y, v1.z, v1.w};

    u16 ob[64];
#pragma unroll
    for (int j = 0; j < 8; ++j) {
        float xj = xv[j];
        float p1 = c1x * xj + c1c;
        ob[j * 8 + 0] = f2bf(p1);
        float pm2 = 1.f, pm1 = p1;
#pragma unroll
        for (int n = 2; n <= 8; ++n) {
            float pn = ((2.f * xj - An[n]) * pm1 - Cn[n] * pm2) * Sn[n];
            ob[j * 8 + n - 1] = f2bf(pn);
            pm2 = pm1; pm1 = pn;
        }
    }

    uint4* dst = (uint4*)(A + (size_t)rb * K_DIM + (size_t)i0 * 8);
    const uint4* s = (const uint4*)ob;
#pragma unroll
    for (int u = 0; u < 8; ++u) dst[u] = s[u];
}

__global__ __launch_bounds__(256) void aw_prep(
    const float* __restrict__ coeffs, const float* __restrict__ x,
    const float* __restrict__ pa, const float* __restrict__ pb,
    const float* __restrict__ pc, const float* __restrict__ pd,
    const float* __restrict__ pq,
    u16* __restrict__ Bt, float* __restrict__ bias, u16* __restrict__ A)
{
    __shared__ float lds[32][292];
    int blk = blockIdx.x;
    int t = threadIdx.x;
    if (blk < 1024) {
        do_transform_block(blk, t, coeffs, Bt, bias, lds);
    } else {
        int gt = (blk - 1024) * 256 + t;
        do_basis_thread(gt, x, pa, pb, pc, pd, pq, A, 0);
    }
}

__global__ __launch_bounds__(256) void aw_transform(
    const float* __restrict__ coeffs, u16* __restrict__ Bt, float* __restrict__ bias)
{
    __shared__ float lds[32][292];
    do_transform_block(blockIdx.x, threadIdx.x, coeffs, Bt, bias, lds);
}

__global__ void aw_basis(const float* __restrict__ x,
                         const float* __restrict__ pa, const float* __restrict__ pb,
                         const float* __restrict__ pc, const float* __restrict__ pd,
                         const float* __restrict__ pq,
                         u16* __restrict__ A, int row0)
{
    do_basis_thread(blockIdx.x * 256 + threadIdx.x, x, pa, pb, pc, pd, pq, A, row0);
}

// ---------------------------------------------------------------------------
// Kernel 2: 128x128-PER-WAVE split-K GEMM.
// BM=BN=256, BK=64, 256 thr = 4 waves (2Mx2N), each owning 128x128 output
// (acc 8x8 f32x4 = 256 regs, unified VGPR/AGPR file, 1 wave/SIMD).
// Square per-wave tile cuts LDS reads to 250 B/MFMA (+125 write) -> LDS
// service (~2070 cyc/tile/CU) < MFMA wall (2480) : MFMA-bound at last.
// Double-buffered 128 KB LDS, r14-verified free-flow ledger:
//   stage(t+1) -> buf (t+1)&1 (16 gload_lds, issued first; ~3000-cyc window)
//   per ks: 16 ds_read_b128 frags ; 64 MFMA (setprio)
//   vmcnt(0) ; s_barrier       (depth-1: full drain is the only correct wait)
// Split-K across blocks: khSplit=2 -> 256 wg (1/CU); kh0 writes C, kh1
// writes part1; aw_reduce sums + bias. Verified slot^(r&7) swizzle (ks1
// offsets = ks0 ^ 64, compile-time). XCD swizzle groups each rowBlk's
// 4 colBlk x 2 kh neighbors on one XCD (A panels = 4 MB = one L2).
// ---------------------------------------------------------------------------
__global__ __launch_bounds__(256, 1) void aw_gemm(
    const u16* __restrict__ A,
    const u16* __restrict__ B,
    float* __restrict__ C,
    float* __restrict__ part1,
    int row0, int rowBlocks, int khSplit)
{
    __shared__ alignas(16) u16 As[2 * A_TILE];   // 64 KB
    __shared__ alignas(16) u16 Bs[2 * B_TILE];   // 64 KB

    int nwg = rowBlocks * 4 * khSplit;
    int bid = blockIdx.x;
    int logical = bid;
    if ((nwg & 7) == 0) {
        int per = nwg >> 3;
        logical = (bid & 7) * per + (bid >> 3);
    }
    int rowBlk = logical / (4 * khSplit);
    int rem    = logical - rowBlk * (4 * khSplit);
    int colBlk = rem / khSplit;          // 0..3
    int kh     = rem - colBlk * khSplit; // 0..khSplit-1

    const int nTiles = NT_FULL / khSplit;
    const int kBase  = kh * nTiles * BK;  // element offset in K

    const int tid  = threadIdx.x;
    const int lane = tid & 63;
    const int wid  = tid >> 6;
    const int wr = wid >> 1;             // 2 M-waves (128 rows each)
    const int wc = wid & 1;              // 2 N-waves (128 cols each)

    // --- staging addresses: 8 A + 8 B gload_lds per thread; pre-swizzled ---
    const u16* gA[8]; const u16* gB[8];
#pragma unroll
    for (int j = 0; j < 8; ++j) {
        int idx = j * 256 + tid;
        int r = idx >> 3, sl = idx & 7;
        int col = ((sl ^ (r & 7)) << 3);
        gA[j] = A + (size_t)(rowBlk * BM + r) * K_DIM + kBase + col;
        gB[j] = B + (size_t)(colBlk * BN + r) * K_DIM + kBase + col;
    }
    const int ldsOff = tid << 3;         // + j*2048 per round

    // --- fragment byte-offsets, ks0 (ks1 = ^64, since s0<4 and +4 flips bit2) ---
    int offA[8], offB[8];
#pragma unroll
    for (int mi = 0; mi < 8; ++mi) {
        int r = wr * 128 + mi * 16 + (lane & 15);
        int s = (lane >> 4);             // ks=0
        offA[mi] = r * 128 + ((s ^ (r & 7)) << 4);
    }
#pragma unroll
    for (int ni = 0; ni < 8; ++ni) {
        int r = wc * 128 + ni * 16 + (lane & 15);
        int s = (lane >> 4);
        offB[ni] = r * 128 + ((s ^ (r & 7)) << 4);
    }

    f32x4 acc[8][8];
#pragma unroll
    for (int mi = 0; mi < 8; ++mi)
#pragma unroll
        for (int ni = 0; ni < 8; ++ni)
            acc[mi][ni] = (f32x4){0.f, 0.f, 0.f, 0.f};

    auto stage = [&](int kt, int buf) {
        const int k0 = kt * BK;
        u16* dA = As + buf * A_TILE;
        u16* dB = Bs + buf * B_TILE;
#pragma unroll
        for (int j = 0; j < 8; ++j) gload_lds16(gA[j] + k0, dA + ldsOff + j * 2048);
#pragma unroll
        for (int j = 0; j < 8; ++j) gload_lds16(gB[j] + k0, dB + ldsOff + j * 2048);
    };

    // prologue: stage tile 0, full drain
    stage(0, 0);
    asm volatile("s_waitcnt vmcnt(0)" ::: "memory");
    __builtin_amdgcn_s_barrier();

    for (int t = 0; t < nTiles; ++t) {
        const bool pf = (t + 1 < nTiles);
        if (pf) stage(t + 1, (t + 1) & 1);

        const char* aB = (const char*)(As + (t & 1) * A_TILE);
        const char* bB = (const char*)(Bs + (t & 1) * B_TILE);

#pragma unroll
        for (int ks = 0; ks < 2; ++ks) {
            const int x1 = ks ? 64 : 0;   // ks1 swizzled-offset delta
            bf16x8 fa[8], fb[8];
#pragma unroll
            for (int mi = 0; mi < 8; ++mi) fa[mi] = *(const bf16x8*)(aB + (offA[mi] ^ x1));
#pragma unroll
            for (int ni = 0; ni < 8; ++ni) fb[ni] = *(const bf16x8*)(bB + (offB[ni] ^ x1));

            __builtin_amdgcn_s_setprio(1);
#pragma unroll
            for (int mi = 0; mi < 8; ++mi)
#pragma unroll
                for (int ni = 0; ni < 8; ++ni)
                    acc[mi][ni] = __builtin_amdgcn_mfma_f32_16x16x32_bf16(
                        fa[mi], fb[ni], acc[mi][ni], 0, 0, 0);
            __builtin_amdgcn_s_setprio(0);
        }

        if (pf) {
            asm volatile("s_waitcnt vmcnt(0)" ::: "memory");
            __builtin_amdgcn_s_barrier();
        }
    }

    // epilogue: direct write (no LDS reuse). D layout col=lane&15,
    // row=(lane>>4)*4+j [m89]. No bias here (reduce adds it).
    float* dstBase = (kh == 0) ? C : part1;
    int gRow = row0 + rowBlk * BM + wr * 128;
    int gCol = colBlk * BN + wc * 128;
#pragma unroll
    for (int mi = 0; mi < 8; ++mi) {
#pragma unroll
        for (int ni = 0; ni < 8; ++ni) {
            int rr = gRow + mi * 16 + ((lane >> 4) << 2);
            int cc = gCol + ni * 16 + (lane & 15);
            float* dst = dstBase + (size_t)rr * N_DIM + cc;
#pragma unroll
            for (int j = 0; j < 4; ++j) dst[(size_t)j * N_DIM] = acc[mi][ni][j];
        }
    }
}

// ---------------------------------------------------------------------------
// Kernel 3: out += part1 (if addPart) + bias.  100 MB @ ~6 TB/s ~= 17 us.
// ---------------------------------------------------------------------------
__global__ __launch_bounds__(256) void aw_reduce(
    float* __restrict__ out, const float* __restrict__ part1,
    const float* __restrict__ bias, int addPart)
{
    const int total4 = M_DIM * N_DIM / 4;         // 2M f32x4
    f32x4* o4 = (f32x4*)out;
    const f32x4* p4 = (const f32x4*)part1;
    const f32x4* b4 = (const f32x4*)bias;
    for (int i = blockIdx.x * 256 + threadIdx.x; i < total4; i += gridDim.x * 256) {
        f32x4 v = o4[i];
        if (addPart) v += p4[i];
        v += b4[i & (N_DIM / 4 - 1)];
        o4[i] = v;
    }
}

// ---------------------------------------------------------------------------
extern "C" void kernel_launch(void* const* d_in, const int* in_sizes, int n_in,
                              void* d_out, int out_size, void* d_ws, size_t ws_size,
                              hipStream_t stream)
{
    const float* x      = (const float*)d_in[0];
    const float* pa     = (const float*)d_in[1];
    const float* pb     = (const float*)d_in[2];
    const float* pc     = (const float*)d_in[3];
    const float* pd     = (const float*)d_in[4];
    const float* pq     = (const float*)d_in[5];
    const float* coeffs = (const float*)d_in[6];
    float* out = (float*)d_out;

    float* bias = (float*)d_ws;
    const size_t biasBytes = 4096;
    u16* Bt = (u16*)((char*)d_ws + biasBytes);
    const size_t btBytes = (size_t)N_DIM * K_DIM * sizeof(u16);     // 16.8 MB
    u16* Abuf = (u16*)((char*)d_ws + biasBytes + btBytes);
    const size_t aFullBytes = (size_t)M_DIM * K_DIM * sizeof(u16);  // 134 MB
    const size_t partBytes  = (size_t)M_DIM * N_DIM * sizeof(float);// 33.5 MB
    size_t used = biasBytes + btBytes;
    size_t avail = ws_size > used ? ws_size - used : 0;

    hipMemsetAsync(bias, 0, N_DIM * sizeof(float), stream);

    if (avail >= aFullBytes) {
        float* part1 = (float*)((char*)d_ws + biasBytes + btBytes + aFullBytes);
        int khSplit = (avail >= aFullBytes + partBytes) ? 2 : 1;

        aw_prep<<<1024 + (M_DIM * 128) / 256, 256, 0, stream>>>(
            coeffs, x, pa, pb, pc, pd, pq, Bt, bias, Abuf);
        int rowBlocks = M_DIM / BM;                      // 32
        aw_gemm<<<rowBlocks * 4 * khSplit, 256, 0, stream>>>(
            Abuf, Bt, out, part1, 0, rowBlocks, khSplit);
        aw_reduce<<<2048, 256, 0, stream>>>(out, part1, bias, khSplit == 2 ? 1 : 0);
    } else {
        // chunked fallback (khSplit=1, no partial buffer needed)
        int chunk = M_DIM;
        while (chunk > 256 && (size_t)chunk * K_DIM * sizeof(u16) > avail) chunk >>= 1;
        aw_transform<<<1024, 256, 0, stream>>>(coeffs, Bt, bias);
        for (int row0 = 0; row0 < M_DIM; row0 += chunk) {
            aw_basis<<<(chunk * 128) / 256, 256, 0, stream>>>(x, pa, pb, pc, pd, pq, Abuf, row0);
            aw_gemm<<<(chunk / BM) * 4, 256, 0, stream>>>(
                Abuf, Bt, out, out, row0, chunk / BM, 1);
        }
        aw_reduce<<<2048, 256, 0, stream>>>(out, out, bias, 0);
    }
}

// Round 17
// 180.795 us; speedup vs baseline: 1.8710x; 1.1189x over previous
//
#include <hip/hip_runtime.h>
#include <cstdint>

typedef unsigned short u16;
typedef __bf16 bf16x8 __attribute__((ext_vector_type(8)));
typedef float f32x4 __attribute__((ext_vector_type(4)));

#define M_DIM 8192
#define N_DIM 1024
#define I_DIM 1024
#define NDEG 8                    /* stored degrees d=1..8 */
#define K_DIM (I_DIM * NDEG)      /* 8192 */
#define BM 256
#define BN 128
#define BK 64
#define NT (K_DIM / BK)           /* 128 K-tiles */
#define A_TILE (BM * BK)          /* 16384 u16 = 32 KB */
#define B_TILE (BN * BK)          /* 8192  u16 = 16 KB */

__device__ __forceinline__ u16 f2bf(float f) {
    union { float f; uint32_t u; } v; v.f = f;
    return (u16)((v.u + 0x7FFFu + ((v.u >> 16) & 1u)) >> 16);
}

__device__ __forceinline__ void gload_lds16(const u16* g, u16* l) {
    auto lp = reinterpret_cast<__attribute__((address_space(3))) uint32_t*>(
        reinterpret_cast<uintptr_t>(l));
    __builtin_amdgcn_global_load_lds(reinterpret_cast<const uint32_t*>(g), lp, 16, 0, 0);
}

// ---------------------------------------------------------------------------
// fused prep helpers (r11-verified)
// ---------------------------------------------------------------------------
__device__ __forceinline__ void do_transform_block(
    int blk, int t, const float* __restrict__ coeffs,
    u16* __restrict__ Bt, float* __restrict__ bias, float (*lds)[292])
{
    int bi = blk >> 5, bo = blk & 31;
    int i0 = bi * 32, o0 = bo * 32;

    {
        int r = t >> 3, s = t & 7;
        const float4* src = (const float4*)(coeffs + ((size_t)(i0 + r) * N_DIM + o0) * 9);
#pragma unroll
        for (int j = 0; j < 9; ++j) {
            float4 v = src[s * 9 + j];
            *(float4*)&lds[r][(s * 9 + j) * 4] = v;
        }
    }
    __syncthreads();

    {
        int c = t >> 3, s2 = t & 7;
        u16 ob[32];
#pragma unroll
        for (int rr = 0; rr < 4; ++rr)
#pragma unroll
            for (int dd = 0; dd < 8; ++dd)
                ob[rr * 8 + dd] = f2bf(lds[s2 * 4 + rr][c * 9 + 1 + dd]);
        uint4* dst = (uint4*)(Bt + (size_t)(o0 + c) * K_DIM + (size_t)i0 * 8 + s2 * 32);
        const uint4* sp = (const uint4*)ob;
#pragma unroll
        for (int u = 0; u < 4; ++u) dst[u] = sp[u];
    }

    if (t < 32) {
        float sum = 0.f;
#pragma unroll
        for (int rr = 0; rr < 32; ++rr) sum += lds[rr][t * 9];
        atomicAdd(&bias[o0 + t], sum);
    }
}

__device__ __forceinline__ void do_basis_thread(
    int gt, const float* __restrict__ x,
    const float* __restrict__ pa, const float* __restrict__ pb,
    const float* __restrict__ pc, const float* __restrict__ pd,
    const float* __restrict__ pq, u16* __restrict__ A, int row0)
{
    int rb = gt >> 7;
    int g  = gt & 127;
    int i0 = g << 3;
    int b  = row0 + rb;

    float a = *pa, bb = *pb, c = *pc, d = *pd, q = *pq;
    float ab = a * bb, cd = c * d, abcd = ab * cd;

    float qp[17];
    qp[0] = 1.f;
#pragma unroll
    for (int k = 1; k <= 16; ++k) qp[k] = qp[k - 1] * q;

    float den1 = 1.f + abcd * q * q;
    float c1x = 2.f * (1.f + ab * q) / den1;
    float c1c = -(a + bb) * (1.f + cd * q) / den1;

    float An[9], Cn[9], Sn[9];
#pragma unroll
    for (int n = 2; n <= 8; ++n) {
        float t1 = 1.f - ab * qp[n - 1];
        float t2 = 1.f - cd * qp[n - 1];
        float t3 = 1.f - abcd * qp[2 * n - 2];
        float t4 = 1.f - abcd * qp[2 * n - 1];
        float t5 = 1.f - abcd * qp[2 * n];
        An[n] = (t1 * t2 * t3) / (t4 * t5);
        Cn[n] = ((1.f - qp[n]) * t1 * t2 * t3) / (t3 * t4);
        Sn[n] = 1.f / (1.f - qp[n]);
    }

    const float4* x4 = (const float4*)(x + (size_t)b * I_DIM + i0);
    float4 v0 = x4[0], v1 = x4[1];
    float xv[8] = {v0.x, v0.y, v0.z, v0.w, v1.x, v1.y, v1.z, v1.w};

    u16 ob[64];
#pragma unroll
    for (int j = 0; j < 8; ++j) {
        float xj = xv[j];
        float p1 = c1x * xj + c1c;
        ob[j * 8 + 0] = f2bf(p1);
        float pm2 = 1.f, pm1 = p1;
#pragma unroll
        for (int n = 2; n <= 8; ++n) {
            float pn = ((2.f * xj - An[n]) * pm1 - Cn[n] * pm2) * Sn[n];
            ob[j * 8 + n - 1] = f2bf(pn);
            pm2 = pm1; pm1 = pn;
        }
    }

    uint4* dst = (uint4*)(A + (size_t)rb * K_DIM + (size_t)i0 * 8);
    const uint4* s = (const uint4*)ob;
#pragma unroll
    for (int u = 0; u < 8; ++u) dst[u] = s[u];
}

// ---------------------------------------------------------------------------
// Kernel 1 (fused prep): blocks [0,1024) transform coeffs; blocks
// [1024, 1024+4096) compute the basis for all 8192 rows. Both memory-bound
// and independent -> one dispatch streams ~222 MB. (r11: verified)
// ---------------------------------------------------------------------------
__global__ __launch_bounds__(256) void aw_prep(
    const float* __restrict__ coeffs, const float* __restrict__ x,
    const float* __restrict__ pa, const float* __restrict__ pb,
    const float* __restrict__ pc, const float* __restrict__ pd,
    const float* __restrict__ pq,
    u16* __restrict__ Bt, float* __restrict__ bias, u16* __restrict__ A)
{
    __shared__ float lds[32][292];
    int blk = blockIdx.x;
    int t = threadIdx.x;
    if (blk < 1024) {
        do_transform_block(blk, t, coeffs, Bt, bias, lds);
    } else {
        int gt = (blk - 1024) * 256 + t;
        do_basis_thread(gt, x, pa, pb, pc, pd, pq, A, 0);
    }
}

__global__ __launch_bounds__(256) void aw_transform(
    const float* __restrict__ coeffs, u16* __restrict__ Bt, float* __restrict__ bias)
{
    __shared__ float lds[32][292];
    do_transform_block(blockIdx.x, threadIdx.x, coeffs, Bt, bias, lds);
}

__global__ void aw_basis(const float* __restrict__ x,
                         const float* __restrict__ pa, const float* __restrict__ pb,
                         const float* __restrict__ pc, const float* __restrict__ pd,
                         const float* __restrict__ pq,
                         u16* __restrict__ A, int row0)
{
    do_basis_thread(blockIdx.x * 256 + threadIdx.x, x, pa, pb, pc, pd, pq, A, row0);
}

// ---------------------------------------------------------------------------
// Kernel 2: K-paired free-flow GEMM (r8/r11 best measured: 129.1-129.4 us,
// MfmaUtil 46.6%, 0 bank conflicts). BM=256 x BN=128, BK=64, 512 thr =
// 8 waves: 4 quadrant-owners (2M x 2N, 128x64/wave = 8x4 frags) x 2
// K-halves. Triple-buffered LDS (144 KiB); free-flow interior, ONE counted
// vmcnt(6) + ONE barrier per K-tile. Verified slot^(r&7) swizzle. K-half
// partials merged via LDS epilogue (extra __syncthreads() before the merge
// closes the r8-era write-after-read window on the aliased buffers).
// T1 XCD swizzle, T5 setprio.
// ---------------------------------------------------------------------------
__global__ __launch_bounds__(512) void aw_gemm(
    const u16* __restrict__ A,
    const u16* __restrict__ B,
    const float* __restrict__ bias,
    float* __restrict__ C,
    int row0, int rowBlocks)
{
    __shared__ alignas(16) u16 smem[3 * A_TILE + 3 * B_TILE];   // 144 KB
    u16* As = smem;
    u16* Bs = smem + 3 * A_TILE;

    int nwg = rowBlocks * 8;
    int bid = blockIdx.x;
    int per = nwg >> 3;
    int logical = (bid & 7) * per + (bid >> 3);
    int rowBlk = logical >> 3;       // 8 col-blocks
    int colBlk = logical & 7;

    const int tid  = threadIdx.x;
    const int lane = tid & 63;
    const int wid  = tid >> 6;
    const int quad = wid & 3;        // 4 C-quadrants (2M x 2N)
    const int wr   = quad >> 1;      // 0..1 (128-row half)
    const int wc   = quad & 1;       // 0..1 (64-col half)
    const int myKs = wid >> 2;       // 0..1 (32-wide K half of each tile)

    // --- staging addresses (k0 added per tile); source slot pre-swizzled ---
    const u16* gA[4]; const u16* gB[2];
    int ldsA[4], ldsB[2];
#pragma unroll
    for (int j = 0; j < 4; ++j) {
        int idx = j * 512 + tid;
        int r = idx >> 3, sl = idx & 7;
        gA[j] = A + (size_t)rowBlk * BM * K_DIM + (size_t)r * K_DIM + ((sl ^ (r & 7)) << 3);
        ldsA[j] = idx << 3;
    }
#pragma unroll
    for (int j = 0; j < 2; ++j) {
        int idx = j * 512 + tid;
        int r = idx >> 3, sl = idx & 7;
        gB[j] = B + (size_t)colBlk * BN * K_DIM + (size_t)r * K_DIM + ((sl ^ (r & 7)) << 3);
        ldsB[j] = idx << 3;
    }

    // --- fragment byte-offsets for this wave's ks-half (swizzled reads) ---
    int offA[8], offB[4];
#pragma unroll
    for (int mi = 0; mi < 8; ++mi) {
        int r = wr * 128 + mi * 16 + (lane & 15);
        int s = myKs * 4 + (lane >> 4);
        offA[mi] = r * 128 + ((s ^ (r & 7)) << 4);
    }
#pragma unroll
    for (int ni = 0; ni < 4; ++ni) {
        int r = wc * 64 + ni * 16 + (lane & 15);
        int s = myKs * 4 + (lane >> 4);
        offB[ni] = r * 128 + ((s ^ (r & 7)) << 4);
    }

    f32x4 acc[8][4];
#pragma unroll
    for (int mi = 0; mi < 8; ++mi)
#pragma unroll
        for (int ni = 0; ni < 4; ++ni)
            acc[mi][ni] = (f32x4){0.f, 0.f, 0.f, 0.f};

    auto stage = [&](int kt, int buf) {
        const int k0 = kt * BK;
        u16* dA = As + buf * A_TILE;
        u16* dB = Bs + buf * B_TILE;
        gload_lds16(gA[0] + k0, dA + ldsA[0]);
        gload_lds16(gA[1] + k0, dA + ldsA[1]);
        gload_lds16(gA[2] + k0, dA + ldsA[2]);
        gload_lds16(gA[3] + k0, dA + ldsA[3]);
        gload_lds16(gB[0] + k0, dB + ldsB[0]);
        gload_lds16(gB[1] + k0, dB + ldsB[1]);
    };

    // prologue: 2 tiles in flight (12 loads), wait for tile 0
    stage(0, 0);
    stage(1, 1);
    asm volatile("s_waitcnt vmcnt(6)" ::: "memory");
    __builtin_amdgcn_s_barrier();

    int buf = 0;
    for (int t = 0; t < NT; ++t) {
        const char* aB = (const char*)(As + buf * A_TILE);
        const char* bB = (const char*)(Bs + buf * B_TILE);
        int nb = buf + 2; if (nb >= 3) nb -= 3;
        const bool pf = (t + 2 < NT);

        // fragment reads for this wave's ks-half; prefetch issue interleaved.
        bf16x8 fa[8], fb[4];
#pragma unroll
        for (int mi = 0; mi < 4; ++mi) fa[mi] = *(const bf16x8*)(aB + offA[mi]);
#pragma unroll
        for (int ni = 0; ni < 2; ++ni) fb[ni] = *(const bf16x8*)(bB + offB[ni]);
        if (pf) stage(t + 2, nb);
#pragma unroll
        for (int mi = 4; mi < 8; ++mi) fa[mi] = *(const bf16x8*)(aB + offA[mi]);
#pragma unroll
        for (int ni = 2; ni < 4; ++ni) fb[ni] = *(const bf16x8*)(bB + offB[ni]);

        __builtin_amdgcn_s_setprio(1);
#pragma unroll
        for (int mi = 0; mi < 8; ++mi)
#pragma unroll
            for (int ni = 0; ni < 4; ++ni)
                acc[mi][ni] = __builtin_amdgcn_mfma_f32_16x16x32_bf16(
                    fa[mi], fb[ni], acc[mi][ni], 0, 0, 0);
        __builtin_amdgcn_s_setprio(0);

        // single counted drain + single barrier per K-tile
        if (pf)              { asm volatile("s_waitcnt vmcnt(6)" ::: "memory"); }
        else if (t + 1 < NT) { asm volatile("s_waitcnt vmcnt(0)" ::: "memory"); }
        __builtin_amdgcn_s_barrier();

        buf += 1; if (buf >= 3) buf -= 3;
    }

    // ---- epilogue: merge K-half partials via LDS (128 KB of the 144) ----
    __syncthreads();   // all waves' last-tile reads done before buffer reuse
    float* red = (float*)smem;
    if (myKs == 1) {
        f32x4* dst = (f32x4*)red + quad * 2048;   // 32 KB per quadrant
#pragma unroll
        for (int mi = 0; mi < 8; ++mi)
#pragma unroll
            for (int ni = 0; ni < 4; ++ni)
                dst[(mi * 4 + ni) * 64 + lane] = acc[mi][ni];
    }
    __syncthreads();
    if (myKs == 0) {
        const f32x4* src = (const f32x4*)red + quad * 2048;
#pragma unroll
        for (int mi = 0; mi < 8; ++mi)
#pragma unroll
            for (int ni = 0; ni < 4; ++ni) {
                f32x4 p = src[(mi * 4 + ni) * 64 + lane];
                acc[mi][ni] += p;
            }

        // D layout col=lane&15, row=(lane>>4)*4+j  [m89]
        int gRow = row0 + rowBlk * BM + wr * 128;
        int gCol = colBlk * BN + wc * 64;
#pragma unroll
        for (int mi = 0; mi < 8; ++mi) {
#pragma unroll
            for (int ni = 0; ni < 4; ++ni) {
                int rr = gRow + mi * 16 + ((lane >> 4) << 2);
                int cc = gCol + ni * 16 + (lane & 15);
                float bv = bias[cc];
                float* dst = C + (size_t)rr * N_DIM + cc;
#pragma unroll
                for (int j = 0; j < 4; ++j) dst[(size_t)j * N_DIM] = acc[mi][ni][j] + bv;
            }
        }
    }
}

// ---------------------------------------------------------------------------
extern "C" void kernel_launch(void* const* d_in, const int* in_sizes, int n_in,
                              void* d_out, int out_size, void* d_ws, size_t ws_size,
                              hipStream_t stream)
{
    const float* x      = (const float*)d_in[0];
    const float* pa     = (const float*)d_in[1];
    const float* pb     = (const float*)d_in[2];
    const float* pc     = (const float*)d_in[3];
    const float* pd     = (const float*)d_in[4];
    const float* pq     = (const float*)d_in[5];
    const float* coeffs = (const float*)d_in[6];
    float* out = (float*)d_out;

    float* bias = (float*)d_ws;
    const size_t biasBytes = 4096;
    u16* Bt = (u16*)((char*)d_ws + biasBytes);
    const size_t btBytes = (size_t)N_DIM * K_DIM * sizeof(u16);   // 16.8 MB
    u16* Abuf = (u16*)((char*)d_ws + biasBytes + btBytes);
    size_t used = biasBytes + btBytes;
    size_t avail = ws_size > used ? ws_size - used : 0;
    const size_t aFullBytes = (size_t)M_DIM * K_DIM * sizeof(u16);  // 134 MB

    hipMemsetAsync(bias, 0, N_DIM * sizeof(float), stream);

    if (avail >= aFullBytes) {
        aw_prep<<<1024 + (M_DIM * 128) / 256, 256, 0, stream>>>(
            coeffs, x, pa, pb, pc, pd, pq, Bt, bias, Abuf);
        aw_gemm<<<(M_DIM / BM) * 8, 512, 0, stream>>>(Abuf, Bt, bias, out, 0, M_DIM / BM);
    } else {
        int chunk = M_DIM;
        while (chunk > 256 && (size_t)chunk * K_DIM * sizeof(u16) > avail) chunk >>= 1;
        aw_transform<<<1024, 256, 0, stream>>>(coeffs, Bt, bias);
        for (int row0 = 0; row0 < M_DIM; row0 += chunk) {
            aw_basis<<<(chunk * 128) / 256, 256, 0, stream>>>(x, pa, pb, pc, pd, pq, Abuf, row0);
            aw_gemm<<<(chunk / BM) * 8, 512, 0, stream>>>(Abuf, Bt, bias, out, row0, chunk / BM);
        }
    }
}